// Round 4
// baseline (137.904 us; speedup 1.0000x reference)
//
#include <hip/hip_runtime.h>

typedef __attribute__((ext_vector_type(8))) short short8v;
typedef __attribute__((ext_vector_type(4))) short short4v;
typedef __attribute__((ext_vector_type(4))) float float4v;

// fp32 -> bf16 via native cast: compiler emits v_cvt_pk_bf16_f32 (RNE).
__device__ __forceinline__ short f2bf(float f) {
  __bf16 h = (__bf16)f;
  return __builtin_bit_cast(short, h);
}

// Load 8 contiguous f32 and convert to a bf16x8 MFMA fragment.
__device__ __forceinline__ short8v load_frag8(const float* __restrict__ p) {
  float4 a = *reinterpret_cast<const float4*>(p);
  float4 b = *reinterpret_cast<const float4*>(p + 4);
  short8v r;
  r[0] = f2bf(a.x); r[1] = f2bf(a.y); r[2] = f2bf(a.z); r[3] = f2bf(a.w);
  r[4] = f2bf(b.x); r[5] = f2bf(b.y); r[6] = f2bf(b.z); r[7] = f2bf(b.w);
  return r;
}

constexpr int ROWS = 2;  // rows of x per wave

// One wave handles ROWS rows. Grid = 8192/(4*ROWS) = 1024 blocks x 256 thr
// -> 4 blocks/CU (LDS 32 KB/block, VGPR<=128 via launch_bounds(256,4)),
// 16 waves/CU for latency hiding. Weights (A,B) + bias live in registers;
// bias is folded into the stage-2 accumulator init. Y1^T bounces through a
// single per-wave LDS buffer (XOR-swizzled); no __syncthreads — wave-local
// lgkmcnt fence only (DS pipe is in-order per wave, and the compiler cannot
// reorder aliasing LDS ops across the memory-clobber fence).
__global__ __launch_bounds__(256, 4)
void kron64_kernel(const float* __restrict__ x, const float* __restrict__ A,
                   const float* __restrict__ B, const float* __restrict__ bias,
                   float* __restrict__ out) {
  __shared__ short y1[4][4096];  // 4 waves x 64x64 bf16 (Y1^T) = 32 KB

  const int tid = threadIdx.x;
  const int w = tid >> 6;
  const int lane = tid & 63;
  const int g = lane >> 4;      // lane group 0..3
  const int c = lane & 15;      // lane-in-group 0..15
  const int swz = (c & 7) << 3; // element-index XOR swizzle
  const int m0 = (blockIdx.x * 4 + w) * ROWS;

  // ---- persistent per-wave state: B,A fragments + bias (in D-layout) ----
  short8v bfrag[4][2];  // frag(qt,kk)[i] = B[16qt+c][32kk+8g+i]
  short8v afrag[4][2];  // frag(pt,kk)[i] = A[16pt+c][32kk+8g+i]
  float4v biasf[4][4];  // tile (pt,qt): bias[(16pt+c)*64 + 16qt+4g .. +3]
#pragma unroll
  for (int t = 0; t < 4; ++t)
#pragma unroll
    for (int kk = 0; kk < 2; ++kk) {
      bfrag[t][kk] = load_frag8(B + (16 * t + c) * 64 + 32 * kk + 8 * g);
      afrag[t][kk] = load_frag8(A + (16 * t + c) * 64 + 32 * kk + 8 * g);
    }
#pragma unroll
  for (int pt = 0; pt < 4; ++pt)
#pragma unroll
    for (int qt = 0; qt < 4; ++qt) {
      float4 bv = *reinterpret_cast<const float4*>(
          bias + (16 * pt + c) * 64 + 16 * qt + 4 * g);
      float4v t; t[0] = bv.x; t[1] = bv.y; t[2] = bv.z; t[3] = bv.w;
      biasf[pt][qt] = t;
    }

  const float4v vzero = {0.f, 0.f, 0.f, 0.f};
  short* yw = y1[w];

#pragma unroll
  for (int r = 0; r < ROWS; ++r) {
    const float* xm = x + (size_t)(m0 + r) * 4096;
    // ---------------- Stage 1: C1 = Xm * B^T ----------------
#pragma unroll
    for (int at = 0; at < 4; ++at) {
      float4v acc[4];
#pragma unroll
      for (int qt = 0; qt < 4; ++qt) acc[qt] = vzero;
#pragma unroll
      for (int kk = 0; kk < 2; ++kk) {
        short8v xfrag = load_frag8(xm + (16 * at + c) * 64 + 32 * kk + 8 * g);
#pragma unroll
        for (int qt = 0; qt < 4; ++qt)
          acc[qt] = __builtin_amdgcn_mfma_f32_16x16x32_bf16(
              xfrag, bfrag[qt][kk], acc[qt], 0, 0, 0);
      }
      // lane holds C1[16at+4g+b][16qt+c]; store transposed Y1T[q][a], swizzled
#pragma unroll
      for (int qt = 0; qt < 4; ++qt) {
        short4v v;
        v[0] = f2bf(acc[qt][0]); v[1] = f2bf(acc[qt][1]);
        v[2] = f2bf(acc[qt][2]); v[3] = f2bf(acc[qt][3]);
        int idx = ((16 * qt + c) * 64 + 16 * at + 4 * g) ^ swz;
        *reinterpret_cast<short4v*>(&yw[idx]) = v;
      }
    }

    // Wave-local fence: order the transpose writes before the reads.
    // (DS pipe is in-order per wave; this pins compiler ordering + drains.)
    __asm__ volatile("s_waitcnt lgkmcnt(0)" ::: "memory");

    // ---------------- Stage 2: C2^T = Y1^T * A^T ----------------
    short8v yfrag[4][2];
#pragma unroll
    for (int qt = 0; qt < 4; ++qt)
#pragma unroll
      for (int kk = 0; kk < 2; ++kk) {
        int idx = (((16 * qt + c) * 64) + 32 * kk + 8 * g) ^ swz;
        yfrag[qt][kk] = *reinterpret_cast<const short8v*>(&yw[idx]);
      }

    float* om = out + (size_t)(m0 + r) * 4096;
#pragma unroll
    for (int pt = 0; pt < 4; ++pt) {
#pragma unroll
      for (int qt = 0; qt < 4; ++qt) {
        float4v acc = biasf[pt][qt];  // bias folded into accumulator init
#pragma unroll
        for (int kk = 0; kk < 2; ++kk)
          acc = __builtin_amdgcn_mfma_f32_16x16x32_bf16(
              yfrag[qt][kk], afrag[pt][kk], acc, 0, 0, 0);
        // lane holds C2[p=16pt+c][q=16qt+4g+b] -> n = p*64+q consecutive in b
        int n = (16 * pt + c) * 64 + 16 * qt + 4 * g;
        *reinterpret_cast<float4v*>(om + n) = acc;  // plain store: L2 merges
      }
    }
  }
}

extern "C" void kernel_launch(void* const* d_in, const int* in_sizes, int n_in,
                              void* d_out, int out_size, void* d_ws, size_t ws_size,
                              hipStream_t stream) {
  (void)in_sizes; (void)n_in; (void)out_size; (void)d_ws; (void)ws_size;
  const float* x    = (const float*)d_in[0];
  const float* A    = (const float*)d_in[1];
  const float* B    = (const float*)d_in[2];
  const float* bias = (const float*)d_in[3];
  float* out = (float*)d_out;

  dim3 grid(1024), block(256);
  hipLaunchKernelGGL(kron64_kernel, grid, block, 0, stream, x, A, B, bias, out);
}

// Round 5
// 64.117 us; speedup vs baseline: 2.1508x; 2.1508x over previous
//
#include <hip/hip_runtime.h>

typedef __attribute__((ext_vector_type(8))) short short8v;
typedef __attribute__((ext_vector_type(4))) short short4v;
typedef __attribute__((ext_vector_type(4))) float float4v;

// fp32 -> bf16 via native cast: compiler emits v_cvt_pk_bf16_f32 (RNE).
__device__ __forceinline__ short f2bf(float f) {
  __bf16 h = (__bf16)f;
  return __builtin_bit_cast(short, h);
}

// Load 8 contiguous f32 and convert to a bf16x8 MFMA fragment.
__device__ __forceinline__ short8v load_frag8(const float* __restrict__ p) {
  float4 a = *reinterpret_cast<const float4*>(p);
  float4 b = *reinterpret_cast<const float4*>(p + 4);
  short8v r;
  r[0] = f2bf(a.x); r[1] = f2bf(a.y); r[2] = f2bf(a.z); r[3] = f2bf(a.w);
  r[4] = f2bf(b.x); r[5] = f2bf(b.y); r[6] = f2bf(b.z); r[7] = f2bf(b.w);
  return r;
}

constexpr int ROWS = 2;  // rows of x per wave

// One wave handles ROWS rows. Grid = 8192/(4*ROWS) = 1024 blocks x 256 thr.
// LDS 32 KB/block; VGPR ~116 (launch_bounds(256,2) — (256,4) forced a 64-VGPR
// budget and spilled ~200 MB of scratch traffic, R4 post-mortem) -> 4
// blocks/CU, 16 waves/CU. Weights (A,B) + bias live in registers; bias is
// folded into the stage-2 accumulator init. Y1^T bounces through a single
// per-wave LDS buffer (XOR-swizzled); no __syncthreads — wave-local lgkmcnt
// fence only (DS pipe is in-order per wave).
__global__ __launch_bounds__(256, 2)
void kron64_kernel(const float* __restrict__ x, const float* __restrict__ A,
                   const float* __restrict__ B, const float* __restrict__ bias,
                   float* __restrict__ out) {
  __shared__ short y1[4][4096];  // 4 waves x 64x64 bf16 (Y1^T) = 32 KB

  const int tid = threadIdx.x;
  const int w = tid >> 6;
  const int lane = tid & 63;
  const int g = lane >> 4;      // lane group 0..3
  const int c = lane & 15;      // lane-in-group 0..15
  const int swz = (c & 7) << 3; // element-index XOR swizzle
  const int m0 = (blockIdx.x * 4 + w) * ROWS;

  // ---- persistent per-wave state: B,A fragments + bias (in D-layout) ----
  short8v bfrag[4][2];  // frag(qt,kk)[i] = B[16qt+c][32kk+8g+i]
  short8v afrag[4][2];  // frag(pt,kk)[i] = A[16pt+c][32kk+8g+i]
  float4v biasf[4][4];  // tile (pt,qt): bias[(16pt+c)*64 + 16qt+4g .. +3]
#pragma unroll
  for (int t = 0; t < 4; ++t)
#pragma unroll
    for (int kk = 0; kk < 2; ++kk) {
      bfrag[t][kk] = load_frag8(B + (16 * t + c) * 64 + 32 * kk + 8 * g);
      afrag[t][kk] = load_frag8(A + (16 * t + c) * 64 + 32 * kk + 8 * g);
    }
#pragma unroll
  for (int pt = 0; pt < 4; ++pt)
#pragma unroll
    for (int qt = 0; qt < 4; ++qt) {
      float4 bv = *reinterpret_cast<const float4*>(
          bias + (16 * pt + c) * 64 + 16 * qt + 4 * g);
      float4v t; t[0] = bv.x; t[1] = bv.y; t[2] = bv.z; t[3] = bv.w;
      biasf[pt][qt] = t;
    }

  const float4v vzero = {0.f, 0.f, 0.f, 0.f};
  short* yw = y1[w];

#pragma unroll
  for (int r = 0; r < ROWS; ++r) {
    const float* xm = x + (size_t)(m0 + r) * 4096;
    // ---------------- Stage 1: C1 = Xm * B^T ----------------
#pragma unroll
    for (int at = 0; at < 4; ++at) {
      float4v acc[4];
#pragma unroll
      for (int qt = 0; qt < 4; ++qt) acc[qt] = vzero;
#pragma unroll
      for (int kk = 0; kk < 2; ++kk) {
        short8v xfrag = load_frag8(xm + (16 * at + c) * 64 + 32 * kk + 8 * g);
#pragma unroll
        for (int qt = 0; qt < 4; ++qt)
          acc[qt] = __builtin_amdgcn_mfma_f32_16x16x32_bf16(
              xfrag, bfrag[qt][kk], acc[qt], 0, 0, 0);
      }
      // lane holds C1[16at+4g+b][16qt+c]; store transposed Y1T[q][a], swizzled
#pragma unroll
      for (int qt = 0; qt < 4; ++qt) {
        short4v v;
        v[0] = f2bf(acc[qt][0]); v[1] = f2bf(acc[qt][1]);
        v[2] = f2bf(acc[qt][2]); v[3] = f2bf(acc[qt][3]);
        int idx = ((16 * qt + c) * 64 + 16 * at + 4 * g) ^ swz;
        *reinterpret_cast<short4v*>(&yw[idx]) = v;
      }
    }

    // Wave-local fence: order the transpose writes before the reads.
    // (DS pipe is in-order per wave; this pins compiler ordering + drains.)
    __asm__ volatile("s_waitcnt lgkmcnt(0)" ::: "memory");

    // ---------------- Stage 2: C2^T = Y1^T * A^T ----------------
    short8v yfrag[4][2];
#pragma unroll
    for (int qt = 0; qt < 4; ++qt)
#pragma unroll
      for (int kk = 0; kk < 2; ++kk) {
        int idx = (((16 * qt + c) * 64) + 32 * kk + 8 * g) ^ swz;
        yfrag[qt][kk] = *reinterpret_cast<const short8v*>(&yw[idx]);
      }

    float* om = out + (size_t)(m0 + r) * 4096;
#pragma unroll
    for (int pt = 0; pt < 4; ++pt) {
#pragma unroll
      for (int qt = 0; qt < 4; ++qt) {
        float4v acc = biasf[pt][qt];  // bias folded into accumulator init
#pragma unroll
        for (int kk = 0; kk < 2; ++kk)
          acc = __builtin_amdgcn_mfma_f32_16x16x32_bf16(
              yfrag[qt][kk], afrag[pt][kk], acc, 0, 0, 0);
        // lane holds C2[p=16pt+c][q=16qt+4g+b] -> n = p*64+q consecutive in b
        int n = (16 * pt + c) * 64 + 16 * qt + 4 * g;
        *reinterpret_cast<float4v*>(om + n) = acc;  // plain store: L2 merges
      }
    }
  }
}

extern "C" void kernel_launch(void* const* d_in, const int* in_sizes, int n_in,
                              void* d_out, int out_size, void* d_ws, size_t ws_size,
                              hipStream_t stream) {
  (void)in_sizes; (void)n_in; (void)out_size; (void)d_ws; (void)ws_size;
  const float* x    = (const float*)d_in[0];
  const float* A    = (const float*)d_in[1];
  const float* B    = (const float*)d_in[2];
  const float* bias = (const float*)d_in[3];
  float* out = (float*)d_out;

  dim3 grid(1024), block(256);
  hipLaunchKernelGGL(kron64_kernel, grid, block, 0, stream, x, A, B, bias, out);
}

// Round 6
// 57.330 us; speedup vs baseline: 2.4054x; 1.1184x over previous
//
#include <hip/hip_runtime.h>

typedef __attribute__((ext_vector_type(8))) short short8v;
typedef __attribute__((ext_vector_type(4))) short short4v;
typedef __attribute__((ext_vector_type(4))) float float4v;

// fp32 -> bf16 via native cast: compiler emits v_cvt_pk_bf16_f32 (RNE).
__device__ __forceinline__ short f2bf(float f) {
  __bf16 h = (__bf16)f;
  return __builtin_bit_cast(short, h);
}

// Load 8 contiguous f32 and convert to a bf16x8 MFMA fragment.
__device__ __forceinline__ short8v load_frag8(const float* __restrict__ p) {
  float4 a = *reinterpret_cast<const float4*>(p);
  float4 b = *reinterpret_cast<const float4*>(p + 4);
  short8v r;
  r[0] = f2bf(a.x); r[1] = f2bf(a.y); r[2] = f2bf(a.z); r[3] = f2bf(a.w);
  r[4] = f2bf(b.x); r[5] = f2bf(b.y); r[6] = f2bf(b.z); r[7] = f2bf(b.w);
  return r;
}

// Stage a 64x64 f32 matrix into LDS as bf16, XOR-swizzled:
// element (r, col) -> dst[r*64 + (col ^ ((r&7)<<3))].
// Thread t handles row r=t>>2, cols (t&3)*16..+15 (coalesced global reads;
// two b128 LDS writes, <=2-way bank conflict).
__device__ __forceinline__ void stage_weight(const float* __restrict__ src,
                                             short* __restrict__ dst, int tid) {
  const int r = tid >> 2;
  const int c0 = (tid & 3) << 4;
  const float* p = src + r * 64 + c0;
  float4 f0 = reinterpret_cast<const float4*>(p)[0];
  float4 f1 = reinterpret_cast<const float4*>(p)[1];
  float4 f2 = reinterpret_cast<const float4*>(p)[2];
  float4 f3 = reinterpret_cast<const float4*>(p)[3];
  short8v g0, g1;
  g0[0] = f2bf(f0.x); g0[1] = f2bf(f0.y); g0[2] = f2bf(f0.z); g0[3] = f2bf(f0.w);
  g0[4] = f2bf(f1.x); g0[5] = f2bf(f1.y); g0[6] = f2bf(f1.z); g0[7] = f2bf(f1.w);
  g1[0] = f2bf(f2.x); g1[1] = f2bf(f2.y); g1[2] = f2bf(f2.z); g1[3] = f2bf(f2.w);
  g1[4] = f2bf(f3.x); g1[5] = f2bf(f3.y); g1[6] = f2bf(f3.z); g1[7] = f2bf(f3.w);
  const int sw = (r & 7) << 3;
  *reinterpret_cast<short8v*>(&dst[r * 64 + ((c0)     ^ sw)]) = g0;
  *reinterpret_cast<short8v*>(&dst[r * 64 + ((c0 + 8) ^ sw)]) = g1;
}

// One wave per row m. Grid = 2048 blocks x 256 threads.
// Weights live in block-shared LDS (staged once, bf16, swizzled) instead of
// 128 persistent VGPRs (R5's occupancy cap). Per-wave register peak ~80 ->
// launch_bounds(256,3) caps at ~85 VGPR -> 3 blocks/CU (LDS 48 KB) = 12
// waves/CU. Y1^T bounces through per-wave LDS (swizzled); wave-local lgkmcnt
// fence only between transpose write and read.
__global__ __launch_bounds__(256, 3)
void kron64_kernel(const float* __restrict__ x, const float* __restrict__ A,
                   const float* __restrict__ B, const float* __restrict__ bias,
                   float* __restrict__ out) {
  __shared__ short bw[4096];     // B bf16 [64][64] swizzled, 8 KB
  __shared__ short aw[4096];     // A bf16 [64][64] swizzled, 8 KB
  __shared__ short y1[4][4096];  // per-wave Y1^T, 32 KB

  const int tid = threadIdx.x;
  const int w = tid >> 6;
  const int lane = tid & 63;
  const int g = lane >> 4;       // lane group 0..3
  const int c = lane & 15;       // lane-in-group 0..15
  const int swz = (c & 7) << 3;  // element-index XOR swizzle (row&7 == c&7)

  stage_weight(B, bw, tid);
  stage_weight(A, aw, tid);
  __syncthreads();

  const int m = blockIdx.x * 4 + w;
  const float* xm = x + (size_t)m * 4096;
  short* yw = y1[w];
  const float4v vzero = {0.f, 0.f, 0.f, 0.f};

  // ---------------- Stage 1: C1 = Xm * B^T ----------------
  {
    short8v bfr[4][2];  // frag(qt,kk)[i] = B[16qt+c][32kk+8g+i]
#pragma unroll
    for (int qt = 0; qt < 4; ++qt)
#pragma unroll
      for (int kk = 0; kk < 2; ++kk)
        bfr[qt][kk] = *reinterpret_cast<const short8v*>(
            &bw[(16 * qt + c) * 64 + ((32 * kk + 8 * g) ^ swz)]);

#pragma unroll
    for (int at = 0; at < 4; ++at) {
      float4v acc[4];
#pragma unroll
      for (int qt = 0; qt < 4; ++qt) acc[qt] = vzero;
#pragma unroll
      for (int kk = 0; kk < 2; ++kk) {
        short8v xfrag = load_frag8(xm + (16 * at + c) * 64 + 32 * kk + 8 * g);
#pragma unroll
        for (int qt = 0; qt < 4; ++qt)
          acc[qt] = __builtin_amdgcn_mfma_f32_16x16x32_bf16(
              xfrag, bfr[qt][kk], acc[qt], 0, 0, 0);
      }
      // lane holds C1[16at+4g+b][16qt+c]; store transposed Y1T[q][a], swizzled
#pragma unroll
      for (int qt = 0; qt < 4; ++qt) {
        short4v v;
        v[0] = f2bf(acc[qt][0]); v[1] = f2bf(acc[qt][1]);
        v[2] = f2bf(acc[qt][2]); v[3] = f2bf(acc[qt][3]);
        int idx = ((16 * qt + c) * 64 + 16 * at + 4 * g) ^ swz;
        *reinterpret_cast<short4v*>(&yw[idx]) = v;
      }
    }
  }

  // Wave-local fence: order the transpose writes before the reads.
  __asm__ volatile("s_waitcnt lgkmcnt(0)" ::: "memory");

  // ---------------- Stage 2: C2^T = Y1^T * A^T ----------------
  {
    short8v yfr[4][2];
#pragma unroll
    for (int qt = 0; qt < 4; ++qt)
#pragma unroll
      for (int kk = 0; kk < 2; ++kk) {
        int idx = (((16 * qt + c) * 64) + 32 * kk + 8 * g) ^ swz;
        yfr[qt][kk] = *reinterpret_cast<const short8v*>(&yw[idx]);
      }

    float* om = out + (size_t)m * 4096;
#pragma unroll
    for (int pt = 0; pt < 4; ++pt) {
      short8v afr[2];  // frag(kk)[i] = A[16pt+c][32kk+8g+i]
#pragma unroll
      for (int kk = 0; kk < 2; ++kk)
        afr[kk] = *reinterpret_cast<const short8v*>(
            &aw[(16 * pt + c) * 64 + ((32 * kk + 8 * g) ^ swz)]);
#pragma unroll
      for (int qt = 0; qt < 4; ++qt) {
        // lane holds C2[p=16pt+c][q=16qt+4g+b] -> n = p*64+q consecutive in b
        const int n = (16 * pt + c) * 64 + 16 * qt + 4 * g;
        float4 bv = *reinterpret_cast<const float4*>(bias + n);
        float4v acc; acc[0] = bv.x; acc[1] = bv.y; acc[2] = bv.z; acc[3] = bv.w;
#pragma unroll
        for (int kk = 0; kk < 2; ++kk)
          acc = __builtin_amdgcn_mfma_f32_16x16x32_bf16(
              yfr[qt][kk], afr[kk], acc, 0, 0, 0);
        *reinterpret_cast<float4v*>(om + n) = acc;
      }
    }
  }
}

extern "C" void kernel_launch(void* const* d_in, const int* in_sizes, int n_in,
                              void* d_out, int out_size, void* d_ws, size_t ws_size,
                              hipStream_t stream) {
  (void)in_sizes; (void)n_in; (void)out_size; (void)d_ws; (void)ws_size;
  const float* x    = (const float*)d_in[0];
  const float* A    = (const float*)d_in[1];
  const float* B    = (const float*)d_in[2];
  const float* bias = (const float*)d_in[3];
  float* out = (float*)d_out;

  dim3 grid(2048), block(256);
  hipLaunchKernelGGL(kron64_kernel, grid, block, 0, stream, x, A, B, bias, out);
}